// Round 1
// baseline (297.601 us; speedup 1.0000x reference)
//
#include <hip/hip_runtime.h>
#include <cstdint>

static constexpr int LDR = 8192;   // B * D elements per encoder row

typedef uint16_t u16;
typedef __attribute__((ext_vector_type(8))) short short8;
typedef __attribute__((ext_vector_type(4))) float f32x4;
struct alignas(8) U16x4 { u16 x, y, z, w; };

__device__ __forceinline__ u16 f2bf(float f) {
    union { float f; unsigned u; } v; v.f = f;
    unsigned r = v.u + 0x7fffu + ((v.u >> 16) & 1u);
    return (u16)(r >> 16);
}

__device__ __forceinline__ short8 cvt8(const float4 a, const float4 b) {
    short8 r;
    r[0]=(short)f2bf(a.x); r[1]=(short)f2bf(a.y); r[2]=(short)f2bf(a.z); r[3]=(short)f2bf(a.w);
    r[4]=(short)f2bf(b.x); r[5]=(short)f2bf(b.y); r[6]=(short)f2bf(b.z); r[7]=(short)f2bf(b.w);
    return r;
}

// All GEMM operands are pre-converted bf16 now.
// MODE 1: dvals[r][e]   A=XT_bf (ld 1024)          B=W12_bf (ld 1024)      K=1024
// MODE 2: PT[b][i][m]   A=W3_bf (ld 512)           B=Enc_bf rows m (ld 8192, +z*512) K=512
// MODE 3: HT[b][i][e1]  A=PT_bf (ld 1024)          B=EncT_bf (ld 1024)     K=1024
// MODE 4: out[l,b,i]    A=dvals_bf (row l*16+z)    B=HT_bf (ld 512)        K=512
template<int MODE>
__device__ __forceinline__ const short8* a_ptr(const u16* A, int row, int kk, int z) {
    if constexpr (MODE == 1)      return (const short8*)(A + row*1024 + kk);
    else if constexpr (MODE == 2) return (const short8*)(A + row*512 + kk);
    else if constexpr (MODE == 3) return (const short8*)(A + z*524288 + row*1024 + kk);
    else                          return (const short8*)(A + (row*16 + z)*512 + kk);
}
template<int MODE>
__device__ __forceinline__ const short8* b_ptr(const u16* B, int row, int kk, int z) {
    if constexpr (MODE == 1)      return (const short8*)(B + row*1024 + kk);
    else if constexpr (MODE == 2) return (const short8*)(B + row*8192 + z*512 + kk);
    else if constexpr (MODE == 3) return (const short8*)(B + z*524288 + row*1024 + kk);
    else                          return (const short8*)(B + z*262144 + row*512 + kk);
}

template<int MODE>
__global__ __launch_bounds__(256) void gemm_bf16(
    const u16* __restrict__ A, const u16* __restrict__ Bm,
    const float* __restrict__ b1, const float* __restrict__ b2,
    const float* __restrict__ b3, const float* __restrict__ Sinv,
    u16* __restrict__ Cb, float* __restrict__ Cf)
{
    constexpr int K = (MODE == 2 || MODE == 4) ? 512 : 1024;
    __shared__ __align__(16) u16 As[128 * 40];
    __shared__ __align__(16) u16 Bs[128 * 40];
    const int z    = blockIdx.z;
    const int row0 = blockIdx.y * 128;
    const int col0 = blockIdx.x * 128;
    const int tid  = threadIdx.x;
    const int lane = tid & 63, w = tid >> 6;
    const int wm = w >> 1, wn = w & 1;
    const int quad = lane >> 4, l16 = lane & 15;
    const int crow = tid >> 2, ck8 = (tid & 3) * 8;

    f32x4 acc[4][4] = {};
    short8 pa0 = *a_ptr<MODE>(A,  row0+crow,    ck8, z);
    short8 pa1 = *a_ptr<MODE>(A,  row0+crow+64, ck8, z);
    short8 pb0 = *b_ptr<MODE>(Bm, col0+crow,    ck8, z);
    short8 pb1 = *b_ptr<MODE>(Bm, col0+crow+64, ck8, z);

    for (int kb = 0; kb < K; kb += 32) {
        *(short8*)&As[crow*40 + ck8]      = pa0;
        *(short8*)&As[(crow+64)*40 + ck8] = pa1;
        *(short8*)&Bs[crow*40 + ck8]      = pb0;
        *(short8*)&Bs[(crow+64)*40 + ck8] = pb1;
        __syncthreads();
        if (kb + 32 < K) {
            const int kn = kb + 32 + ck8;
            pa0 = *a_ptr<MODE>(A,  row0+crow,    kn, z);
            pa1 = *a_ptr<MODE>(A,  row0+crow+64, kn, z);
            pb0 = *b_ptr<MODE>(Bm, col0+crow,    kn, z);
            pb1 = *b_ptr<MODE>(Bm, col0+crow+64, kn, z);
        }
        short8 af[4], bfr[4];
        #pragma unroll
        for (int i = 0; i < 4; ++i)
            af[i] = *(const short8*)&As[(wm*64 + i*16 + l16)*40 + quad*8];
        #pragma unroll
        for (int j = 0; j < 4; ++j)
            bfr[j] = *(const short8*)&Bs[(wn*64 + j*16 + l16)*40 + quad*8];
        #pragma unroll
        for (int i = 0; i < 4; ++i)
            #pragma unroll
            for (int j = 0; j < 4; ++j)
                acc[i][j] = __builtin_amdgcn_mfma_f32_16x16x32_bf16(af[i], bfr[j], acc[i][j], 0, 0, 0);
        __syncthreads();
    }

    #pragma unroll
    for (int i = 0; i < 4; ++i) {
        const int grow = row0 + wm*64 + i*16 + quad*4;
        #pragma unroll
        for (int j = 0; j < 4; ++j) {
            const int gcol = col0 + wn*64 + j*16 + l16;
            #pragma unroll
            for (int r = 0; r < 4; ++r) {
                float v = acc[i][j][r];
                const int R = grow + r;
                if constexpr (MODE == 1) {
                    v += b1[gcol] + b2[gcol];
                    Cb[R*512 + gcol] = f2bf(v);
                } else if constexpr (MODE == 2) {
                    Cb[z*524288 + R*1024 + gcol] = f2bf(v);
                } else if constexpr (MODE == 3) {
                    Cb[z*262144 + R*512 + gcol] = f2bf(v);
                } else {
                    const float s = Sinv[R*16 + z];
                    Cf[(R*16 + z)*512 + gcol] = v * s + b3[gcol];
                }
            }
        }
    }
}

// EncT_bf[b][e][m] <- bf16(enc[m][b][e]) via 64x64 LDS tiles; also emits
// elementwise Enc_bf[m][b][e] (coalesced) so gemm<2> never touches fp32.
__global__ __launch_bounds__(256) void enct_kernel(
    const float* __restrict__ E, u16* __restrict__ EncT, u16* __restrict__ Encb)
{
    __shared__ float tile[64][65];
    const int bb = blockIdx.z;
    const int m0 = blockIdx.y * 64;
    const int e0 = blockIdx.x * 64;
    const int t = threadIdx.x;
    const int tr = t >> 4;
    const int tc4 = (t & 15) * 4;
    #pragma unroll
    for (int it = 0; it < 4; ++it) {
        const int ml = tr + it*16;
        float4 v = *(const float4*)&E[(m0+ml)*LDR + bb*512 + e0 + tc4];
        *(float4*)&tile[ml][tc4] = v;
        U16x4 o;
        o.x = f2bf(v.x); o.y = f2bf(v.y); o.z = f2bf(v.z); o.w = f2bf(v.w);
        *(U16x4*)&Encb[(m0+ml)*LDR + bb*512 + e0 + tc4] = o;
    }
    __syncthreads();
    #pragma unroll
    for (int it = 0; it < 4; ++it) {
        const int el = tr + it*16;
        U16x4 o;
        o.x = f2bf(tile[tc4+0][el]);
        o.y = f2bf(tile[tc4+1][el]);
        o.z = f2bf(tile[tc4+2][el]);
        o.w = f2bf(tile[tc4+3][el]);
        *(U16x4*)&EncT[bb*524288 + (e0+el)*1024 + m0 + tc4] = o;
    }
}

// XT_bf[r][k]: k<512 from X, k>=512 from T (row r = l*16+b). Lives in d_out.
__global__ __launch_bounds__(256) void xt_kernel(
    const float* __restrict__ X, const float* __restrict__ T, u16* __restrict__ XT)
{
    const int idx = blockIdx.x * 256 + threadIdx.x;   // 2,097,152 threads, 8 elems each
    const int k8 = (idx & 127) * 8;
    const int r  = idx >> 7;
    const float* src = (k8 < 512) ? (X + r*512 + k8) : (T + r*512 + (k8 - 512));
    float4 a = *(const float4*)src;
    float4 b = *((const float4*)src + 1);
    *(short8*)&XT[r*1024 + k8] = cvt8(a, b);
}

// W12_bf[e][k] = bf16(W1[e][k] | W2[e][k-512]); W3_bf[i][k] = bf16(W3[i][k])
__global__ __launch_bounds__(256) void w_kernel(
    const float* __restrict__ W1, const float* __restrict__ W2,
    const float* __restrict__ W3, u16* __restrict__ W12, u16* __restrict__ W3b)
{
    const int idx = blockIdx.x * 256 + threadIdx.x;
    if (idx < 65536) {          // W12: 512 rows x 128 chunks
        const int r = idx >> 7, k8 = (idx & 127) * 8;
        const float* src = (k8 < 512) ? (W1 + r*512 + k8) : (W2 + r*512 + (k8 - 512));
        float4 a = *(const float4*)src;
        float4 b = *((const float4*)src + 1);
        *(short8*)&W12[r*1024 + k8] = cvt8(a, b);
    } else {                    // W3: 512 rows x 64 chunks
        const int i2 = idx - 65536;
        const int r = i2 >> 6, k8 = (i2 & 63) * 8;
        const float* src = W3 + r*512 + k8;
        float4 a = *(const float4*)src;
        float4 b = *((const float4*)src + 1);
        *(short8*)&W3b[r*512 + k8] = cvt8(a, b);
    }
}

__global__ __launch_bounds__(256) void encsum_partial(
    const float* __restrict__ E, double* __restrict__ part)
{
    const int t  = blockIdx.x * 256 + threadIdx.x;  // b*512+e
    const int cy = blockIdx.y;
    double a = 0.0;
    for (int m = 0; m < 128; ++m) a += (double)E[(cy*128 + m)*LDR + t];
    part[cy*LDR + t] = a;
}

__global__ __launch_bounds__(256) void encsum_final(
    const double* __restrict__ part, double* __restrict__ es)
{
    const int t = blockIdx.x * 256 + threadIdx.x;
    double a = 0.0;
    #pragma unroll
    for (int c = 0; c < 8; ++c) a += part[c*LDR + t];
    es[t] = a;
}

// u[which][b][i] = sum_e W[e*512+i] * es[b*512+e]
__global__ __launch_bounds__(256) void u_kernel(
    const float* __restrict__ W1, const float* __restrict__ W2,
    const double* __restrict__ es, double* __restrict__ u)
{
    const int t = blockIdx.x * 256 + threadIdx.x;  // 0..8191
    const int which = blockIdx.y;
    const float* W = which ? W2 : W1;
    const int b = t >> 9, i = t & 511;
    double a = 0.0;
    for (int e = 0; e < 512; ++e) a += (double)W[e*512 + i] * es[b*512 + e];
    u[which*8192 + t] = a;
}

__global__ __launch_bounds__(256) void c_kernel(
    const float* __restrict__ b1, const float* __restrict__ b2,
    const double* __restrict__ es, double* __restrict__ cd)
{
    __shared__ double red[256];
    const int b = blockIdx.x, t = threadIdx.x;
    double a = 0.0;
    for (int e = t; e < 512; e += 256) a += (double)(b1[e] + b2[e]) * es[b*512 + e];
    red[t] = a; __syncthreads();
    for (int s = 128; s > 0; s >>= 1) { if (t < s) red[t] += red[t+s]; __syncthreads(); }
    if (t == 0) cd[b] = red[0];
}

// Sinv[r] = 1 / ( X[r,:]·u1[b] + T[r,:]·u2[b] + c[b] ),  b = r%16, fp64
__global__ __launch_bounds__(256) void s_kernel(
    const float* __restrict__ X, const float* __restrict__ T,
    const double* __restrict__ u, const double* __restrict__ cd,
    float* __restrict__ Sinv)
{
    const int wave = threadIdx.x >> 6, lane = threadIdx.x & 63;
    const int r = blockIdx.x * 4 + wave;
    const int b = r & 15;
    const double* u1 = u + b*512;
    const double* u2 = u + 8192 + b*512;
    double a = 0.0;
    for (int e = lane*4; e < 512; e += 256) {
        float4 x  = *(const float4*)&X[r*512 + e];
        float4 t4 = *(const float4*)&T[r*512 + e];
        a += (double)x.x*u1[e] + (double)x.y*u1[e+1] + (double)x.z*u1[e+2] + (double)x.w*u1[e+3];
        a += (double)t4.x*u2[e] + (double)t4.y*u2[e+1] + (double)t4.z*u2[e+2] + (double)t4.w*u2[e+3];
    }
    #pragma unroll
    for (int off = 32; off > 0; off >>= 1) a += __shfl_down(a, off, 64);
    if (lane == 0) Sinv[r] = (float)(1.0 / (a + cd[b]));
}

extern "C" void kernel_launch(void* const* d_in, const int* in_sizes, int n_in,
                              void* d_out, int out_size, void* d_ws, size_t ws_size,
                              hipStream_t stream)
{
    const float* X   = (const float*)d_in[0];
    const float* Enc = (const float*)d_in[1];
    const float* T   = (const float*)d_in[2];
    const float* W1  = (const float*)d_in[3];
    const float* b1  = (const float*)d_in[4];
    const float* W2  = (const float*)d_in[5];
    const float* b2  = (const float*)d_in[6];
    const float* W3  = (const float*)d_in[7];
    const float* b3  = (const float*)d_in[8];
    float* out = (float*)d_out;

    char* w = (char*)d_ws;
    // Enc_bf (gemm<2> B-operand) and dvals_bf share one region: gemm<1> writes
    // dvals AFTER gemm<2> has consumed Enc_bf (stream-ordered).
    u16*    EncAlias = (u16*)(w);                 // 16,777,216 B (Enc_bf, then dvals_bf)
    u16*    PT_bf    = (u16*)(w + 16777216);      // 16,777,216 B
    u16*    EncT_bf  = (u16*)(w + 33554432);      // 16,777,216 B
    u16*    HT_bf    = (u16*)(w + 50331648);      //  8,388,608 B
    u16*    W12      = (u16*)(w + 58720256);      //  1,048,576 B
    u16*    W3b      = (u16*)(w + 59768832);      //    524,288 B
    double* part     = (double*)(w + 60293120);   //    524,288 B
    double* es       = (double*)(w + 60817408);   //     65,536 B
    double* u        = (double*)(w + 60882944);   //    131,072 B
    double* cd       = (double*)(w + 61014016);   //        128 B
    float*  Sinv     = (float*)(w + 61014144);    //     65,536 B  (end 61,079,680)
    // XT_bf lives in d_out (exactly 32 MiB); consumed by gemm<1>, then gemm<4>
    // overwrites d_out with the real output.
    u16*    XTb      = (u16*)d_out;
    u16*    Enc_bf   = EncAlias;
    u16*    dvals_bf = EncAlias;

    dim3 blk(256);
    enct_kernel   <<<dim3(8, 16, 16), blk, 0, stream>>>(Enc, EncT_bf, Enc_bf);
    encsum_partial<<<dim3(32, 8),     blk, 0, stream>>>(Enc, part);
    encsum_final  <<<dim3(32),        blk, 0, stream>>>(part, es);
    u_kernel      <<<dim3(32, 2),     blk, 0, stream>>>(W1, W2, es, u);
    c_kernel      <<<dim3(16),        blk, 0, stream>>>(b1, b2, es, cd);
    s_kernel      <<<dim3(4096),      blk, 0, stream>>>(X, T, u, cd, Sinv);
    w_kernel      <<<dim3(384),       blk, 0, stream>>>(W1, W2, W3, W12, W3b);
    xt_kernel     <<<dim3(8192),      blk, 0, stream>>>(X, T, XTb);

    // PT[b] = W3 x Enc_b^T
    gemm_bf16<2><<<dim3(8, 4, 16),  blk, 0, stream>>>(W3b, Enc_bf, b1, b2, b3, Sinv, PT_bf, out);
    // HT[b] = PT_b x Enc_b  (= W3 x Gram(Enc_b))
    gemm_bf16<3><<<dim3(4, 4, 16),  blk, 0, stream>>>(PT_bf, EncT_bf, b1, b2, b3, Sinv, HT_bf, out);
    // dvals = XT x W12^T + b1 + b2   (overwrites Enc_bf region)
    gemm_bf16<1><<<dim3(4, 128, 1), blk, 0, stream>>>(XTb, W12, b1, b2, b3, Sinv, dvals_bf, out);
    // out[l,b,i] = Sinv * (dvals x HT_b^T) + b3
    gemm_bf16<4><<<dim3(4, 8, 16),  blk, 0, stream>>>(dvals_bf, HT_bf, b1, b2, b3, Sinv, dvals_bf, out);
}

// Round 2
// 271.518 us; speedup vs baseline: 1.0961x; 1.0961x over previous
//
#include <hip/hip_runtime.h>
#include <cstdint>

static constexpr int LDR = 8192;   // B * D elements per encoder row

typedef uint16_t u16;
typedef __attribute__((ext_vector_type(8))) short short8;
typedef __attribute__((ext_vector_type(4))) float f32x4;
struct alignas(8) U16x4 { u16 x, y, z, w; };

__device__ __forceinline__ u16 f2bf(float f) {
    union { float f; unsigned u; } v; v.f = f;
    unsigned r = v.u + 0x7fffu + ((v.u >> 16) & 1u);
    return (u16)(r >> 16);
}

__device__ __forceinline__ short8 cvt8(const float4 a, const float4 b) {
    short8 r;
    r[0]=(short)f2bf(a.x); r[1]=(short)f2bf(a.y); r[2]=(short)f2bf(a.z); r[3]=(short)f2bf(a.w);
    r[4]=(short)f2bf(b.x); r[5]=(short)f2bf(b.y); r[6]=(short)f2bf(b.z); r[7]=(short)f2bf(b.w);
    return r;
}

// GEMM modes (all operands pre-converted bf16; C[r,c] = sum_k A[r,k]*B[c,k]):
// MODE 1: dvals[r][e]    A=XT_bf (ld 1024)           B=W12_bf (ld 1024)          K=1024
// MODE 5: Gram[b][e][e'] A=EncT_bf (ld 1024, +z)     B=EncT_bf (same)            K=1024
// MODE 6: HT[b][i][e1]   A=W3_bf (ld 512)            B=Gram (ld 512, +z)         K=512
// MODE 4: out[l,b,i]     A=dvals_bf (row l*16+z)     B=HT_bf (ld 512, +z)        K=512
template<int MODE>
__device__ __forceinline__ const short8* a_ptr(const u16* A, int row, int kk, int z) {
    if constexpr (MODE == 1)      return (const short8*)(A + row*1024 + kk);
    else if constexpr (MODE == 5) return (const short8*)(A + z*524288 + row*1024 + kk);
    else if constexpr (MODE == 6) return (const short8*)(A + row*512 + kk);
    else                          return (const short8*)(A + (row*16 + z)*512 + kk);
}
template<int MODE>
__device__ __forceinline__ const short8* b_ptr(const u16* B, int row, int kk, int z) {
    if constexpr (MODE == 1)      return (const short8*)(B + row*1024 + kk);
    else if constexpr (MODE == 5) return (const short8*)(B + z*524288 + row*1024 + kk);
    else if constexpr (MODE == 6) return (const short8*)(B + z*262144 + row*512 + kk);
    else                          return (const short8*)(B + z*262144 + row*512 + kk);
}

template<int MODE>
__global__ __launch_bounds__(256) void gemm_bf16(
    const u16* __restrict__ A, const u16* __restrict__ Bm,
    const float* __restrict__ b1, const float* __restrict__ b2,
    const float* __restrict__ b3, const float* __restrict__ Sinv,
    u16* __restrict__ Cb, float* __restrict__ Cf)
{
    constexpr int K = (MODE == 1 || MODE == 5) ? 1024 : 512;
    __shared__ __align__(16) u16 As[128 * 40];
    __shared__ __align__(16) u16 Bs[128 * 40];
    const int z    = blockIdx.z;
    const int row0 = blockIdx.y * 128;
    const int col0 = blockIdx.x * 128;
    const int tid  = threadIdx.x;
    const int lane = tid & 63, w = tid >> 6;
    const int wm = w >> 1, wn = w & 1;
    const int quad = lane >> 4, l16 = lane & 15;
    const int crow = tid >> 2, ck8 = (tid & 3) * 8;

    f32x4 acc[4][4] = {};
    short8 pa0 = *a_ptr<MODE>(A,  row0+crow,    ck8, z);
    short8 pa1 = *a_ptr<MODE>(A,  row0+crow+64, ck8, z);
    short8 pb0 = *b_ptr<MODE>(Bm, col0+crow,    ck8, z);
    short8 pb1 = *b_ptr<MODE>(Bm, col0+crow+64, ck8, z);

    for (int kb = 0; kb < K; kb += 32) {
        *(short8*)&As[crow*40 + ck8]      = pa0;
        *(short8*)&As[(crow+64)*40 + ck8] = pa1;
        *(short8*)&Bs[crow*40 + ck8]      = pb0;
        *(short8*)&Bs[(crow+64)*40 + ck8] = pb1;
        __syncthreads();
        if (kb + 32 < K) {
            const int kn = kb + 32 + ck8;
            pa0 = *a_ptr<MODE>(A,  row0+crow,    kn, z);
            pa1 = *a_ptr<MODE>(A,  row0+crow+64, kn, z);
            pb0 = *b_ptr<MODE>(Bm, col0+crow,    kn, z);
            pb1 = *b_ptr<MODE>(Bm, col0+crow+64, kn, z);
        }
        short8 af[4], bfr[4];
        #pragma unroll
        for (int i = 0; i < 4; ++i)
            af[i] = *(const short8*)&As[(wm*64 + i*16 + l16)*40 + quad*8];
        #pragma unroll
        for (int j = 0; j < 4; ++j)
            bfr[j] = *(const short8*)&Bs[(wn*64 + j*16 + l16)*40 + quad*8];
        #pragma unroll
        for (int i = 0; i < 4; ++i)
            #pragma unroll
            for (int j = 0; j < 4; ++j)
                acc[i][j] = __builtin_amdgcn_mfma_f32_16x16x32_bf16(af[i], bfr[j], acc[i][j], 0, 0, 0);
        __syncthreads();
    }

    #pragma unroll
    for (int i = 0; i < 4; ++i) {
        const int grow = row0 + wm*64 + i*16 + quad*4;
        #pragma unroll
        for (int j = 0; j < 4; ++j) {
            const int gcol = col0 + wn*64 + j*16 + l16;
            #pragma unroll
            for (int r = 0; r < 4; ++r) {
                float v = acc[i][j][r];
                const int R = grow + r;
                if constexpr (MODE == 1) {
                    v += b1[gcol] + b2[gcol];
                    Cb[R*512 + gcol] = f2bf(v);
                } else if constexpr (MODE == 5 || MODE == 6) {
                    Cb[z*262144 + R*512 + gcol] = f2bf(v);
                } else {
                    const float s = Sinv[R*16 + z];
                    Cf[(R*16 + z)*512 + gcol] = v * s + b3[gcol];
                }
            }
        }
    }
}

// EncT_bf[b][e][m] <- bf16(enc[m][b][e]) via 64x64 LDS tiles.
// Also emits fp64 column-sum partials: part[mchunk][b*512+e] = sum of 64 m's.
__global__ __launch_bounds__(256) void enct_kernel(
    const float* __restrict__ E, u16* __restrict__ EncT, double* __restrict__ part)
{
    __shared__ float tile[64][65];
    __shared__ double sred[256];
    const int bb = blockIdx.z;
    const int m0 = blockIdx.y * 64;
    const int e0 = blockIdx.x * 64;
    const int t = threadIdx.x;
    const int tr = t >> 4;
    const int tc4 = (t & 15) * 4;
    #pragma unroll
    for (int it = 0; it < 4; ++it) {
        const int ml = tr + it*16;
        float4 v = *(const float4*)&E[(m0+ml)*LDR + bb*512 + e0 + tc4];
        *(float4*)&tile[ml][tc4] = v;
    }
    __syncthreads();
    #pragma unroll
    for (int it = 0; it < 4; ++it) {
        const int el = tr + it*16;
        U16x4 o;
        o.x = f2bf(tile[tc4+0][el]);
        o.y = f2bf(tile[tc4+1][el]);
        o.z = f2bf(tile[tc4+2][el]);
        o.w = f2bf(tile[tc4+3][el]);
        *(U16x4*)&EncT[bb*524288 + (e0+el)*1024 + m0 + tc4] = o;
    }
    // column partial sums over this block's 64 m's, per e
    const int el = t & 63, mq = t >> 6;
    double a = 0.0;
    #pragma unroll
    for (int j = 0; j < 16; ++j) a += (double)tile[mq*16 + j][el];
    sred[t] = a;
    __syncthreads();
    if (t < 64) {
        double s = sred[t] + sred[t+64] + sred[t+128] + sred[t+192];
        part[blockIdx.y*8192 + bb*512 + e0 + t] = s;
    }
}

// Role-dispatched small-work kernel:
//  blk 0..383  : bf16 conversion of W1|W2 -> W12 and W3 -> W3b
//  blk 384..447: u[which][b][i] = sum_e W[e,i] * es[b,e]   (es from part, in-block)
//  blk 448..463: cd[b] = sum_e (b1[e]+b2[e]) * es[b,e]
__global__ __launch_bounds__(256) void prep_small(
    const float* __restrict__ W1, const float* __restrict__ W2,
    const float* __restrict__ W3, const float* __restrict__ b1,
    const float* __restrict__ b2, const double* __restrict__ part,
    u16* __restrict__ W12, u16* __restrict__ W3b,
    double* __restrict__ u, double* __restrict__ cd)
{
    const int blk = blockIdx.x, tid = threadIdx.x;
    if (blk < 384) {
        const int idx = blk*256 + tid;
        if (idx < 65536) {          // W12: 512 rows x 128 chunks
            const int r = idx >> 7, k8 = (idx & 127) * 8;
            const float* src = (k8 < 512) ? (W1 + r*512 + k8) : (W2 + r*512 + (k8 - 512));
            float4 a = *(const float4*)src;
            float4 b = *((const float4*)src + 1);
            *(short8*)&W12[r*1024 + k8] = cvt8(a, b);
        } else {                    // W3: 512 rows x 64 chunks
            const int i2 = idx - 65536;
            const int r = i2 >> 6, k8 = (i2 & 63) * 8;
            const float* src = W3 + r*512 + k8;
            float4 a = *(const float4*)src;
            float4 b = *((const float4*)src + 1);
            *(short8*)&W3b[r*512 + k8] = cvt8(a, b);
        }
        return;
    }
    __shared__ double es_l[512];
    __shared__ double red[256];
    int b;
    if (blk < 448) b = ((blk - 384) & 31) >> 1;
    else           b = blk - 448;
    for (int e = tid; e < 512; e += 256) {
        double s = 0.0;
        #pragma unroll
        for (int c = 0; c < 16; ++c) s += part[c*8192 + b*512 + e];
        es_l[e] = s;
    }
    __syncthreads();
    if (blk < 448) {
        const int blk2 = blk - 384;
        const int which = blk2 >> 5;
        const int t = (blk2 & 31)*256 + tid;   // b*512 + i
        const int i = t & 511;
        const float* W = which ? W2 : W1;
        double a = 0.0;
        for (int e = 0; e < 512; ++e) a += (double)W[e*512 + i] * es_l[e];
        u[which*8192 + t] = a;
    } else {
        double a = 0.0;
        for (int e = tid; e < 512; e += 256) a += (double)(b1[e] + b2[e]) * es_l[e];
        red[tid] = a; __syncthreads();
        for (int s = 128; s > 0; s >>= 1) { if (tid < s) red[tid] += red[tid+s]; __syncthreads(); }
        if (tid == 0) cd[b] = red[0];
    }
}

// Fused: Sinv[r] = 1/(X[r,:]·u1[b] + T[r,:]·u2[b] + c[b]) AND XT_bf[r] emission.
// One wave per row; lane owns 8 contiguous elements of X and of T.
__global__ __launch_bounds__(256) void s_xt_kernel(
    const float* __restrict__ X, const float* __restrict__ T,
    const double* __restrict__ u, const double* __restrict__ cd,
    float* __restrict__ Sinv, u16* __restrict__ XT)
{
    const int wave = threadIdx.x >> 6, lane = threadIdx.x & 63;
    const int r = blockIdx.x * 4 + wave;
    const int b = r & 15;
    const double* u1 = u + b*512;
    const double* u2 = u + 8192 + b*512;
    const int e = lane * 8;
    float4 x0 = *(const float4*)&X[r*512 + e];
    float4 x1 = *(const float4*)&X[r*512 + e + 4];
    float4 t0 = *(const float4*)&T[r*512 + e];
    float4 t1 = *(const float4*)&T[r*512 + e + 4];
    double a = 0.0;
    a += (double)x0.x*u1[e+0] + (double)x0.y*u1[e+1] + (double)x0.z*u1[e+2] + (double)x0.w*u1[e+3];
    a += (double)x1.x*u1[e+4] + (double)x1.y*u1[e+5] + (double)x1.z*u1[e+6] + (double)x1.w*u1[e+7];
    a += (double)t0.x*u2[e+0] + (double)t0.y*u2[e+1] + (double)t0.z*u2[e+2] + (double)t0.w*u2[e+3];
    a += (double)t1.x*u2[e+4] + (double)t1.y*u2[e+5] + (double)t1.z*u2[e+6] + (double)t1.w*u2[e+7];
    *(short8*)&XT[r*1024 + e]       = cvt8(x0, x1);
    *(short8*)&XT[r*1024 + 512 + e] = cvt8(t0, t1);
    #pragma unroll
    for (int off = 32; off > 0; off >>= 1) a += __shfl_down(a, off, 64);
    if (lane == 0) Sinv[r] = (float)(1.0 / (a + cd[b]));
}

extern "C" void kernel_launch(void* const* d_in, const int* in_sizes, int n_in,
                              void* d_out, int out_size, void* d_ws, size_t ws_size,
                              hipStream_t stream)
{
    const float* X   = (const float*)d_in[0];
    const float* Enc = (const float*)d_in[1];
    const float* T   = (const float*)d_in[2];
    const float* W1  = (const float*)d_in[3];
    const float* b1  = (const float*)d_in[4];
    const float* W2  = (const float*)d_in[5];
    const float* b2  = (const float*)d_in[6];
    const float* W3  = (const float*)d_in[7];
    const float* b3  = (const float*)d_in[8];
    float* out = (float*)d_out;

    char* w = (char*)d_ws;
    u16*    dvals_bf = (u16*)(w);                 // 16,777,216 B
    u16*    EncT_bf  = (u16*)(w + 16777216);      // 16,777,216 B
    u16*    Gram_bf  = (u16*)(w + 33554432);      //  8,388,608 B
    u16*    HT_bf    = (u16*)(w + 41943040);      //  8,388,608 B
    u16*    W12      = (u16*)(w + 50331648);      //  1,048,576 B
    u16*    W3b      = (u16*)(w + 51380224);      //    524,288 B
    double* part     = (double*)(w + 51904512);   //  1,048,576 B (16 x 8192 f64)
    double* u        = (double*)(w + 52953088);   //    131,072 B
    double* cd       = (double*)(w + 53084160);   //        128 B
    float*  Sinv     = (float*)(w + 53084288);    //     65,536 B  (end 53,149,824)
    // XT_bf lives in d_out (exactly 32 MiB); consumed by gemm<1>, then gemm<4>
    // overwrites d_out with the real output.
    u16*    XTb      = (u16*)d_out;

    dim3 blk(256);
    enct_kernel <<<dim3(8, 16, 16), blk, 0, stream>>>(Enc, EncT_bf, part);
    prep_small  <<<dim3(464),       blk, 0, stream>>>(W1, W2, W3, b1, b2, part, W12, W3b, u, cd);
    s_xt_kernel <<<dim3(4096),      blk, 0, stream>>>(X, T, u, cd, Sinv, XTb);

    // Gram[b] = Enc_b^T x Enc_b   (both operands = EncT_bf rows)
    gemm_bf16<5><<<dim3(4, 4, 16),  blk, 0, stream>>>(EncT_bf, EncT_bf, b1, b2, b3, Sinv, Gram_bf, out);
    // HT[b] = W3 x Gram_b  (Gram symmetric)
    gemm_bf16<6><<<dim3(4, 4, 16),  blk, 0, stream>>>(W3b, Gram_bf, b1, b2, b3, Sinv, HT_bf, out);
    // dvals = XT x W12^T + b1 + b2
    gemm_bf16<1><<<dim3(4, 128, 1), blk, 0, stream>>>(XTb, W12, b1, b2, b3, Sinv, dvals_bf, out);
    // out[l,b,i] = Sinv * (dvals x HT_b^T) + b3
    gemm_bf16<4><<<dim3(4, 8, 16),  blk, 0, stream>>>(dvals_bf, HT_bf, b1, b2, b3, Sinv, dvals_bf, out);
}

// Round 3
// 260.775 us; speedup vs baseline: 1.1412x; 1.0412x over previous
//
#include <hip/hip_runtime.h>
#include <cstdint>

static constexpr int LDR = 8192;   // B * D elements per encoder row

typedef uint16_t u16;
typedef __attribute__((ext_vector_type(8))) short short8;
typedef __attribute__((ext_vector_type(4))) float f32x4;
struct alignas(8) U16x4 { u16 x, y, z, w; };

__device__ __forceinline__ u16 f2bf(float f) {
    union { float f; unsigned u; } v; v.f = f;
    unsigned r = v.u + 0x7fffu + ((v.u >> 16) & 1u);
    return (u16)(r >> 16);
}

__device__ __forceinline__ short8 cvt8(const float4 a, const float4 b) {
    short8 r;
    r[0]=(short)f2bf(a.x); r[1]=(short)f2bf(a.y); r[2]=(short)f2bf(a.z); r[3]=(short)f2bf(a.w);
    r[4]=(short)f2bf(b.x); r[5]=(short)f2bf(b.y); r[6]=(short)f2bf(b.z); r[7]=(short)f2bf(b.w);
    return r;
}

// GEMM modes (all operands pre-converted bf16; C[r,c] = sum_k A[r,k]*B[c,k]):
// MODE 1: dvals[r][e]    A=XT_bf (ld 1024)           B=W12_bf (ld 1024)          K=1024
// MODE 5: Gram[b][e][e'] A=EncT_bf (ld 1024, +z)     B=EncT_bf (same)            K=1024
// MODE 6: HT[b][i][e1]   A=W3_bf (ld 512)            B=Gram (ld 512, +z)         K=512
// MODE 4: out[l,b,i]     A=dvals_bf (row l*16+z)     B=HT_bf (ld 512, +z)        K=512
template<int MODE>
__device__ __forceinline__ const short8* a_ptr(const u16* A, int row, int kk, int z) {
    if constexpr (MODE == 1)      return (const short8*)(A + row*1024 + kk);
    else if constexpr (MODE == 5) return (const short8*)(A + z*524288 + row*1024 + kk);
    else if constexpr (MODE == 6) return (const short8*)(A + row*512 + kk);
    else                          return (const short8*)(A + (row*16 + z)*512 + kk);
}
template<int MODE>
__device__ __forceinline__ const short8* b_ptr(const u16* B, int row, int kk, int z) {
    if constexpr (MODE == 1)      return (const short8*)(B + row*1024 + kk);
    else if constexpr (MODE == 5) return (const short8*)(B + z*524288 + row*1024 + kk);
    else                          return (const short8*)(B + z*262144 + row*512 + kk);
}

// 128x128-tile GEMM (modes 1 and 4): 4 waves, each 64x64 output.
template<int MODE>
__global__ __launch_bounds__(256) void gemm_bf16(
    const u16* __restrict__ A, const u16* __restrict__ Bm,
    const float* __restrict__ b1, const float* __restrict__ b2,
    const float* __restrict__ b3, const float* __restrict__ Sinv,
    u16* __restrict__ Cb, float* __restrict__ Cf)
{
    constexpr int K = (MODE == 1) ? 1024 : 512;
    __shared__ __align__(16) u16 As[128 * 40];
    __shared__ __align__(16) u16 Bs[128 * 40];
    const int z    = blockIdx.z;
    const int row0 = blockIdx.y * 128;
    const int col0 = blockIdx.x * 128;
    const int tid  = threadIdx.x;
    const int lane = tid & 63, w = tid >> 6;
    const int wm = w >> 1, wn = w & 1;
    const int quad = lane >> 4, l16 = lane & 15;
    const int crow = tid >> 2, ck8 = (tid & 3) * 8;

    f32x4 acc[4][4] = {};
    short8 pa0 = *a_ptr<MODE>(A,  row0+crow,    ck8, z);
    short8 pa1 = *a_ptr<MODE>(A,  row0+crow+64, ck8, z);
    short8 pb0 = *b_ptr<MODE>(Bm, col0+crow,    ck8, z);
    short8 pb1 = *b_ptr<MODE>(Bm, col0+crow+64, ck8, z);

    for (int kb = 0; kb < K; kb += 32) {
        *(short8*)&As[crow*40 + ck8]      = pa0;
        *(short8*)&As[(crow+64)*40 + ck8] = pa1;
        *(short8*)&Bs[crow*40 + ck8]      = pb0;
        *(short8*)&Bs[(crow+64)*40 + ck8] = pb1;
        __syncthreads();
        if (kb + 32 < K) {
            const int kn = kb + 32 + ck8;
            pa0 = *a_ptr<MODE>(A,  row0+crow,    kn, z);
            pa1 = *a_ptr<MODE>(A,  row0+crow+64, kn, z);
            pb0 = *b_ptr<MODE>(Bm, col0+crow,    kn, z);
            pb1 = *b_ptr<MODE>(Bm, col0+crow+64, kn, z);
        }
        short8 af[4], bfr[4];
        #pragma unroll
        for (int i = 0; i < 4; ++i)
            af[i] = *(const short8*)&As[(wm*64 + i*16 + l16)*40 + quad*8];
        #pragma unroll
        for (int j = 0; j < 4; ++j)
            bfr[j] = *(const short8*)&Bs[(wn*64 + j*16 + l16)*40 + quad*8];
        #pragma unroll
        for (int i = 0; i < 4; ++i)
            #pragma unroll
            for (int j = 0; j < 4; ++j)
                acc[i][j] = __builtin_amdgcn_mfma_f32_16x16x32_bf16(af[i], bfr[j], acc[i][j], 0, 0, 0);
        __syncthreads();
    }

    #pragma unroll
    for (int i = 0; i < 4; ++i) {
        const int grow = row0 + wm*64 + i*16 + quad*4;
        #pragma unroll
        for (int j = 0; j < 4; ++j) {
            const int gcol = col0 + wn*64 + j*16 + l16;
            #pragma unroll
            for (int r = 0; r < 4; ++r) {
                float v = acc[i][j][r];
                const int R = grow + r;
                if constexpr (MODE == 1) {
                    v += b1[gcol] + b2[gcol];
                    Cb[R*512 + gcol] = f2bf(v);
                } else {
                    const float s = Sinv[R*16 + z];
                    Cf[(R*16 + z)*512 + gcol] = v * s + b3[gcol];
                }
            }
        }
    }
}

// 64x128-tile GEMM (modes 5 and 6): doubles block count for the small
// batched GEMMs (512 blocks -> 2 blocks/CU -> 2 waves/SIMD latency hiding).
// 4 waves, each 64 rows x 32 cols (acc 4x2), 8 MFMA per wave per K-step.
template<int MODE>
__global__ __launch_bounds__(256) void gemm64_bf16(
    const u16* __restrict__ A, const u16* __restrict__ Bm,
    u16* __restrict__ Cb)
{
    constexpr int K = (MODE == 5) ? 1024 : 512;
    __shared__ __align__(16) u16 As[64 * 40];
    __shared__ __align__(16) u16 Bs[128 * 40];
    const int z    = blockIdx.z;
    const int row0 = blockIdx.y * 64;
    const int col0 = blockIdx.x * 128;
    const int tid  = threadIdx.x;
    const int lane = tid & 63, wn = tid >> 6;   // wave covers all 64 rows, 32 cols
    const int quad = lane >> 4, l16 = lane & 15;
    const int crow = tid >> 2, ck8 = (tid & 3) * 8;

    f32x4 acc[4][2] = {};
    short8 pa0 = *a_ptr<MODE>(A,  row0+crow,    ck8, z);
    short8 pb0 = *b_ptr<MODE>(Bm, col0+crow,    ck8, z);
    short8 pb1 = *b_ptr<MODE>(Bm, col0+crow+64, ck8, z);

    for (int kb = 0; kb < K; kb += 32) {
        *(short8*)&As[crow*40 + ck8]      = pa0;
        *(short8*)&Bs[crow*40 + ck8]      = pb0;
        *(short8*)&Bs[(crow+64)*40 + ck8] = pb1;
        __syncthreads();
        if (kb + 32 < K) {
            const int kn = kb + 32 + ck8;
            pa0 = *a_ptr<MODE>(A,  row0+crow,    kn, z);
            pb0 = *b_ptr<MODE>(Bm, col0+crow,    kn, z);
            pb1 = *b_ptr<MODE>(Bm, col0+crow+64, kn, z);
        }
        short8 af[4], bfr[2];
        #pragma unroll
        for (int i = 0; i < 4; ++i)
            af[i] = *(const short8*)&As[(i*16 + l16)*40 + quad*8];
        #pragma unroll
        for (int j = 0; j < 2; ++j)
            bfr[j] = *(const short8*)&Bs[(wn*32 + j*16 + l16)*40 + quad*8];
        #pragma unroll
        for (int i = 0; i < 4; ++i)
            #pragma unroll
            for (int j = 0; j < 2; ++j)
                acc[i][j] = __builtin_amdgcn_mfma_f32_16x16x32_bf16(af[i], bfr[j], acc[i][j], 0, 0, 0);
        __syncthreads();
    }

    #pragma unroll
    for (int i = 0; i < 4; ++i) {
        const int grow = row0 + i*16 + quad*4;
        #pragma unroll
        for (int j = 0; j < 2; ++j) {
            const int gcol = col0 + wn*32 + j*16 + l16;
            #pragma unroll
            for (int r = 0; r < 4; ++r)
                Cb[z*262144 + (grow + r)*512 + gcol] = f2bf(acc[i][j][r]);
        }
    }
}

// EncT_bf[b][e][m] <- bf16(enc[m][b][e]) via 64x64 LDS tiles.
// Also emits fp64 column-sum partials: part[mchunk][b*512+e] = sum of 64 m's.
__global__ __launch_bounds__(256) void enct_kernel(
    const float* __restrict__ E, u16* __restrict__ EncT, double* __restrict__ part)
{
    __shared__ float tile[64][65];
    __shared__ double sred[256];
    const int bb = blockIdx.z;
    const int m0 = blockIdx.y * 64;
    const int e0 = blockIdx.x * 64;
    const int t = threadIdx.x;
    const int tr = t >> 4;
    const int tc4 = (t & 15) * 4;
    #pragma unroll
    for (int it = 0; it < 4; ++it) {
        const int ml = tr + it*16;
        float4 v = *(const float4*)&E[(m0+ml)*LDR + bb*512 + e0 + tc4];
        *(float4*)&tile[ml][tc4] = v;
    }
    __syncthreads();
    #pragma unroll
    for (int it = 0; it < 4; ++it) {
        const int el = tr + it*16;
        U16x4 o;
        o.x = f2bf(tile[tc4+0][el]);
        o.y = f2bf(tile[tc4+1][el]);
        o.z = f2bf(tile[tc4+2][el]);
        o.w = f2bf(tile[tc4+3][el]);
        *(U16x4*)&EncT[bb*524288 + (e0+el)*1024 + m0 + tc4] = o;
    }
    // column partial sums over this block's 64 m's, per e
    const int el = t & 63, mq = t >> 6;
    double a = 0.0;
    #pragma unroll
    for (int j = 0; j < 16; ++j) a += (double)tile[mq*16 + j][el];
    sred[t] = a;
    __syncthreads();
    if (t < 64) {
        double s = sred[t] + sred[t+64] + sred[t+128] + sred[t+192];
        part[blockIdx.y*8192 + bb*512 + e0 + t] = s;
    }
}

// Role-dispatched small-work kernel:
//  blk 0..383  : bf16 conversion of W1|W2 -> W12 and W3 -> W3b
//  blk 384..447: u[which][b][i] = sum_e W[e,i] * es[b,e]   (es from part, in-block)
//  blk 448..463: cd[b] = sum_e (b1[e]+b2[e]) * es[b,e]
__global__ __launch_bounds__(256) void prep_small(
    const float* __restrict__ W1, const float* __restrict__ W2,
    const float* __restrict__ W3, const float* __restrict__ b1,
    const float* __restrict__ b2, const double* __restrict__ part,
    u16* __restrict__ W12, u16* __restrict__ W3b,
    double* __restrict__ u, double* __restrict__ cd)
{
    const int blk = blockIdx.x, tid = threadIdx.x;
    if (blk < 384) {
        const int idx = blk*256 + tid;
        if (idx < 65536) {          // W12: 512 rows x 128 chunks
            const int r = idx >> 7, k8 = (idx & 127) * 8;
            const float* src = (k8 < 512) ? (W1 + r*512 + k8) : (W2 + r*512 + (k8 - 512));
            float4 a = *(const float4*)src;
            float4 b = *((const float4*)src + 1);
            *(short8*)&W12[r*1024 + k8] = cvt8(a, b);
        } else {                    // W3: 512 rows x 64 chunks
            const int i2 = idx - 65536;
            const int r = i2 >> 6, k8 = (i2 & 63) * 8;
            const float* src = W3 + r*512 + k8;
            float4 a = *(const float4*)src;
            float4 b = *((const float4*)src + 1);
            *(short8*)&W3b[r*512 + k8] = cvt8(a, b);
        }
        return;
    }
    __shared__ double es_l[512];
    __shared__ double red[256];
    int b;
    if (blk < 448) b = ((blk - 384) & 31) >> 1;
    else           b = blk - 448;
    for (int e = tid; e < 512; e += 256) {
        double s = 0.0;
        #pragma unroll
        for (int c = 0; c < 16; ++c) s += part[c*8192 + b*512 + e];
        es_l[e] = s;
    }
    __syncthreads();
    if (blk < 448) {
        const int blk2 = blk - 384;
        const int which = blk2 >> 5;
        const int t = (blk2 & 31)*256 + tid;   // b*512 + i
        const int i = t & 511;
        const float* W = which ? W2 : W1;
        double a = 0.0;
        for (int e = 0; e < 512; ++e) a += (double)W[e*512 + i] * es_l[e];
        u[which*8192 + t] = a;
    } else {
        double a = 0.0;
        for (int e = tid; e < 512; e += 256) a += (double)(b1[e] + b2[e]) * es_l[e];
        red[tid] = a; __syncthreads();
        for (int s = 128; s > 0; s >>= 1) { if (tid < s) red[tid] += red[tid+s]; __syncthreads(); }
        if (tid == 0) cd[b] = red[0];
    }
}

// Fused: Sinv[r] = 1/(X[r,:]·u1[b] + T[r,:]·u2[b] + c[b]) AND XT_bf[r] emission.
// One block per (b, row-group): u1/u2 held in REGISTERS (lane k owns exactly
// the 8 u-elements its X/T chunk needs), amortized over 32 rows — kills the
// 134 MB of per-row u re-reads that capped the old version at 1.6 TB/s.
__global__ __launch_bounds__(256) void s_xt_kernel(
    const float* __restrict__ X, const float* __restrict__ T,
    const double* __restrict__ u, const double* __restrict__ cd,
    float* __restrict__ Sinv, u16* __restrict__ XT)
{
    const int wave = threadIdx.x >> 6, lane = threadIdx.x & 63;
    const int b = blockIdx.x & 15, g = blockIdx.x >> 4;   // g in 0..31
    const int e = lane * 8;
    double u1r[8], u2r[8];
    #pragma unroll
    for (int k = 0; k < 8; ++k) {
        u1r[k] = u[b*512 + e + k];
        u2r[k] = u[8192 + b*512 + e + k];
    }
    const double cb = cd[b];
    #pragma unroll 2
    for (int i = 0; i < 8; ++i) {
        const int j = g*32 + wave*8 + i;     // row-within-b, 0..1023
        const int r = j*16 + b;
        float4 x0 = *(const float4*)&X[r*512 + e];
        float4 x1 = *(const float4*)&X[r*512 + e + 4];
        float4 t0 = *(const float4*)&T[r*512 + e];
        float4 t1 = *(const float4*)&T[r*512 + e + 4];
        double a = 0.0;
        a += (double)x0.x*u1r[0] + (double)x0.y*u1r[1] + (double)x0.z*u1r[2] + (double)x0.w*u1r[3];
        a += (double)x1.x*u1r[4] + (double)x1.y*u1r[5] + (double)x1.z*u1r[6] + (double)x1.w*u1r[7];
        a += (double)t0.x*u2r[0] + (double)t0.y*u2r[1] + (double)t0.z*u2r[2] + (double)t0.w*u2r[3];
        a += (double)t1.x*u2r[4] + (double)t1.y*u2r[5] + (double)t1.z*u2r[6] + (double)t1.w*u2r[7];
        *(short8*)&XT[r*1024 + e]       = cvt8(x0, x1);
        *(short8*)&XT[r*1024 + 512 + e] = cvt8(t0, t1);
        #pragma unroll
        for (int off = 32; off > 0; off >>= 1) a += __shfl_down(a, off, 64);
        if (lane == 0) Sinv[r] = (float)(1.0 / (a + cb));
    }
}

extern "C" void kernel_launch(void* const* d_in, const int* in_sizes, int n_in,
                              void* d_out, int out_size, void* d_ws, size_t ws_size,
                              hipStream_t stream)
{
    const float* X   = (const float*)d_in[0];
    const float* Enc = (const float*)d_in[1];
    const float* T   = (const float*)d_in[2];
    const float* W1  = (const float*)d_in[3];
    const float* b1  = (const float*)d_in[4];
    const float* W2  = (const float*)d_in[5];
    const float* b2  = (const float*)d_in[6];
    const float* W3  = (const float*)d_in[7];
    const float* b3  = (const float*)d_in[8];
    float* out = (float*)d_out;

    char* w = (char*)d_ws;
    u16*    dvals_bf = (u16*)(w);                 // 16,777,216 B
    u16*    EncT_bf  = (u16*)(w + 16777216);      // 16,777,216 B
    u16*    Gram_bf  = (u16*)(w + 33554432);      //  8,388,608 B
    u16*    HT_bf    = (u16*)(w + 41943040);      //  8,388,608 B
    u16*    W12      = (u16*)(w + 50331648);      //  1,048,576 B
    u16*    W3b      = (u16*)(w + 51380224);      //    524,288 B
    double* part     = (double*)(w + 51904512);   //  1,048,576 B (16 x 8192 f64)
    double* u        = (double*)(w + 52953088);   //    131,072 B
    double* cd       = (double*)(w + 53084160);   //        128 B
    float*  Sinv     = (float*)(w + 53084288);    //     65,536 B  (end 53,149,824)
    // XT_bf lives in d_out (exactly 32 MiB); consumed by gemm<1>, then gemm<4>
    // overwrites d_out with the real output.
    u16*    XTb      = (u16*)d_out;

    dim3 blk(256);
    enct_kernel <<<dim3(8, 16, 16), blk, 0, stream>>>(Enc, EncT_bf, part);
    prep_small  <<<dim3(464),       blk, 0, stream>>>(W1, W2, W3, b1, b2, part, W12, W3b, u, cd);
    s_xt_kernel <<<dim3(512),       blk, 0, stream>>>(X, T, u, cd, Sinv, XTb);

    // Gram[b] = Enc_b^T x Enc_b   (both operands = EncT_bf rows)
    gemm64_bf16<5><<<dim3(4, 8, 16),  blk, 0, stream>>>(EncT_bf, EncT_bf, Gram_bf);
    // HT[b] = W3 x Gram_b  (Gram symmetric)
    gemm64_bf16<6><<<dim3(4, 8, 16),  blk, 0, stream>>>(W3b, Gram_bf, HT_bf);
    // dvals = XT x W12^T + b1 + b2
    gemm_bf16<1><<<dim3(4, 128, 1), blk, 0, stream>>>(XTb, W12, b1, b2, b3, Sinv, dvals_bf, out);
    // out[l,b,i] = Sinv * (dvals x HT_b^T) + b3
    gemm_bf16<4><<<dim3(4, 8, 16),  blk, 0, stream>>>(dvals_bf, HT_bf, b1, b2, b3, Sinv, dvals_bf, out);
}

// Round 4
// 247.632 us; speedup vs baseline: 1.2018x; 1.0531x over previous
//
#include <hip/hip_runtime.h>
#include <cstdint>

static constexpr int LDR = 8192;   // B * D elements per encoder row

typedef uint16_t u16;
typedef __attribute__((ext_vector_type(8))) short short8;
typedef __attribute__((ext_vector_type(4))) float f32x4;
struct alignas(8) U16x4 { u16 x, y, z, w; };

__device__ __forceinline__ u16 f2bf(float f) {
    union { float f; unsigned u; } v; v.f = f;
    unsigned r = v.u + 0x7fffu + ((v.u >> 16) & 1u);
    return (u16)(r >> 16);
}

__device__ __forceinline__ short8 cvt8(const float4 a, const float4 b) {
    short8 r;
    r[0]=(short)f2bf(a.x); r[1]=(short)f2bf(a.y); r[2]=(short)f2bf(a.z); r[3]=(short)f2bf(a.w);
    r[4]=(short)f2bf(b.x); r[5]=(short)f2bf(b.y); r[6]=(short)f2bf(b.z); r[7]=(short)f2bf(b.w);
    return r;
}

// Direct global->LDS 16B load (CK's m0-based form). LDS dest is wave-uniform;
// HW writes lane l's 16 bytes at m0 + l*16.
__device__ __forceinline__ void gl_lds16(const u16* g, unsigned ldsaddr) {
    asm volatile("s_mov_b32 m0, %0\n\t"
                 "global_load_lds_dwordx4 %1, off"
                 :: "s"(__builtin_amdgcn_readfirstlane(ldsaddr)), "v"(g)
                 : "memory");
}

// GEMM modes (all operands pre-converted bf16; C[r,c] = sum_k A[r,k]*B[c,k]):
// MODE 1: dvals[r][e]    A=XT_bf (ld 1024)           B=W12_bf (ld 1024)      K=1024  BM=128
// MODE 5: Gram[b][e][e'] A=EncT_bf (ld 1024, +z)     B=EncT_bf (same)        K=1024  BM=64
// MODE 6: HT[b][i][e1]   A=W3_bf (ld 512)            B=Gram (ld 512, +z)     K=512   BM=64
// MODE 4: out[l,b,i]     A=dvals_bf (row l*16+z)     B=HT_bf (ld 512, +z)    K=512   BM=128
//
// Async structure (m97/T3): BK=64, double-buffered LDS, global_load_lds(16B)
// staging, ONE barrier per K-step. LDS rows are 128B with XOR swizzle
// off ^= ((row&7)<<4) applied on BOTH the global source address (pre-swizzle)
// and the ds_read address -> 2-way bank aliasing (free).
template<int MODE>
__global__ __launch_bounds__(256) void gemm_async(
    const u16* __restrict__ A, const u16* __restrict__ Bm,
    const float* __restrict__ b1, const float* __restrict__ b2,
    const float* __restrict__ b3, const float* __restrict__ Sinv,
    u16* __restrict__ Cb, float* __restrict__ Cf)
{
    constexpr int K   = (MODE == 1 || MODE == 5) ? 1024 : 512;
    constexpr int BM  = (MODE == 5 || MODE == 6) ? 64 : 128;
    constexpr int NJ  = (BM == 128) ? 4 : 2;     // acc cols per wave (16-wide frags)
    constexpr int NIA = BM / 32;                  // 4096B staging issues for A tile
    constexpr int NIB = 4;                        // B tile is always 128 rows
    constexpr int ASZ = BM * 128;                 // bytes per A buffer
    constexpr int BSZ = 128 * 128;                // bytes per B buffer
    constexpr int LDA = (MODE == 1) ? 1024 : (MODE == 4) ? 8192 : (MODE == 5) ? 1024 : 512;
    constexpr int LDB = (MODE == 1 || MODE == 5) ? 1024 : 512;

    __shared__ __align__(16) u16 lds[(2*ASZ + 2*BSZ) / 2];

    const int z    = blockIdx.z;
    const int row0 = blockIdx.y * BM;
    const int col0 = blockIdx.x * 128;
    const int tid  = threadIdx.x;
    const int l    = tid & 63, w = tid >> 6;
    const int wm   = (BM == 128) ? (w >> 1) : 0;
    const int wn   = (BM == 128) ? (w & 1) : w;
    const int quad = l >> 4, l16 = l & 15;

    // per-mode base pointers (z-batch folded in)
    const u16* Ab = A;
    const u16* Bb = Bm;
    if constexpr (MODE == 4) Ab = A + z*512;          // row r -> (r*16+z)*512 = r*8192 + z*512
    if constexpr (MODE == 5) { Ab = A + z*524288; Bb = Bm + z*524288; }
    if constexpr (MODE == 6) Bb = Bm + z*262144;
    if constexpr (MODE == 4) Bb = Bm + z*262144;

    // staging source pointers: issue i covers rows i*32 + w*8 + (l>>3),
    // bytes ((l&7)*16) ^ ((l>>3)<<4) of the 128B k-chunk (pre-swizzled source).
    const int lq = l >> 3;
    const int loffu = ((l & 7) ^ lq) * 8;             // u16 units
    const u16* gA[NIA];
    #pragma unroll
    for (int i = 0; i < NIA; ++i)
        gA[i] = Ab + (size_t)(row0 + i*32 + w*8 + lq) * LDA + loffu;
    const u16* gB[NIB];
    #pragma unroll
    for (int i = 0; i < NIB; ++i)
        gB[i] = Bb + (size_t)(col0 + i*32 + w*8 + lq) * LDB + loffu;

    const unsigned lbase = (unsigned)(size_t)&lds[0];

    auto stage = [&](int c) {
        #pragma unroll
        for (int i = 0; i < NIA; ++i) {
            gl_lds16(gA[i], lbase + c*ASZ + i*4096 + w*1024);
            gA[i] += 64;
        }
        #pragma unroll
        for (int i = 0; i < NIB; ++i) {
            gl_lds16(gB[i], lbase + 2*ASZ + c*BSZ + i*4096 + w*1024);
            gB[i] += 64;
        }
    };

    f32x4 acc[4][NJ] = {};
    const int swzr = (l16 & 7) << 3;                  // read-side swizzle, u16 units
    const int arow = wm * 64;                         // wave's A-row base within tile
    const int brow = wn * (BM == 128 ? 64 : 32);      // wave's B-row base within tile

    stage(0);
    int cur = 0;
    for (int kb = 0; kb < K; kb += 64) {
        asm volatile("s_waitcnt vmcnt(0)" ::: "memory");
        __syncthreads();
        if (kb + 64 < K) stage(cur ^ 1);
        const int abase = cur * (ASZ/2);
        const int bbase = ASZ + cur * (BSZ/2);
        #pragma unroll
        for (int kk = 0; kk < 2; ++kk) {
            const int koff = (kk*32 + quad*8) ^ swzr;
            short8 af[4], bfr[NJ];
            #pragma unroll
            for (int i = 0; i < 4; ++i)
                af[i] = *(const short8*)&lds[abase + (arow + i*16 + l16)*64 + koff];
            #pragma unroll
            for (int j = 0; j < NJ; ++j)
                bfr[j] = *(const short8*)&lds[bbase + (brow + j*16 + l16)*64 + koff];
            #pragma unroll
            for (int i = 0; i < 4; ++i)
                #pragma unroll
                for (int j = 0; j < NJ; ++j)
                    acc[i][j] = __builtin_amdgcn_mfma_f32_16x16x32_bf16(af[i], bfr[j], acc[i][j], 0, 0, 0);
        }
        cur ^= 1;
    }

    #pragma unroll
    for (int i = 0; i < 4; ++i) {
        const int grow = row0 + arow + i*16 + quad*4;
        #pragma unroll
        for (int j = 0; j < NJ; ++j) {
            const int gcol = col0 + brow + j*16 + l16;
            #pragma unroll
            for (int r = 0; r < 4; ++r) {
                float v = acc[i][j][r];
                const int R = grow + r;
                if constexpr (MODE == 1) {
                    v += b1[gcol] + b2[gcol];
                    Cb[R*512 + gcol] = f2bf(v);
                } else if constexpr (MODE == 5 || MODE == 6) {
                    Cb[z*262144 + R*512 + gcol] = f2bf(v);
                } else {
                    const float s = Sinv[R*16 + z];
                    Cf[(R*16 + z)*512 + gcol] = v * s + b3[gcol];
                }
            }
        }
    }
}

// EncT_bf[b][e][m] <- bf16(enc[m][b][e]) via 64x64 LDS tiles.
// Also emits fp64 column-sum partials: part[mchunk][b*512+e] = sum of 64 m's.
__global__ __launch_bounds__(256) void enct_kernel(
    const float* __restrict__ E, u16* __restrict__ EncT, double* __restrict__ part)
{
    __shared__ float tile[64][65];
    __shared__ double sred[256];
    const int bb = blockIdx.z;
    const int m0 = blockIdx.y * 64;
    const int e0 = blockIdx.x * 64;
    const int t = threadIdx.x;
    const int tr = t >> 4;
    const int tc4 = (t & 15) * 4;
    #pragma unroll
    for (int it = 0; it < 4; ++it) {
        const int ml = tr + it*16;
        float4 v = *(const float4*)&E[(m0+ml)*LDR + bb*512 + e0 + tc4];
        *(float4*)&tile[ml][tc4] = v;
    }
    __syncthreads();
    #pragma unroll
    for (int it = 0; it < 4; ++it) {
        const int el = tr + it*16;
        U16x4 o;
        o.x = f2bf(tile[tc4+0][el]);
        o.y = f2bf(tile[tc4+1][el]);
        o.z = f2bf(tile[tc4+2][el]);
        o.w = f2bf(tile[tc4+3][el]);
        *(U16x4*)&EncT[bb*524288 + (e0+el)*1024 + m0 + tc4] = o;
    }
    // column partial sums over this block's 64 m's, per e
    const int el = t & 63, mq = t >> 6;
    double a = 0.0;
    #pragma unroll
    for (int j = 0; j < 16; ++j) a += (double)tile[mq*16 + j][el];
    sred[t] = a;
    __syncthreads();
    if (t < 64) {
        double s = sred[t] + sred[t+64] + sred[t+128] + sred[t+192];
        part[blockIdx.y*8192 + bb*512 + e0 + t] = s;
    }
}

// Role-dispatched small-work kernel:
//  blk 0..383  : bf16 conversion of W1|W2 -> W12 and W3 -> W3b
//  blk 384..447: u[which][b][i] = sum_e W[e,i] * es[b,e]   (es from part, in-block)
//  blk 448..463: cd[b] = sum_e (b1[e]+b2[e]) * es[b,e]
__global__ __launch_bounds__(256) void prep_small(
    const float* __restrict__ W1, const float* __restrict__ W2,
    const float* __restrict__ W3, const float* __restrict__ b1,
    const float* __restrict__ b2, const double* __restrict__ part,
    u16* __restrict__ W12, u16* __restrict__ W3b,
    double* __restrict__ u, double* __restrict__ cd)
{
    const int blk = blockIdx.x, tid = threadIdx.x;
    if (blk < 384) {
        const int idx = blk*256 + tid;
        if (idx < 65536) {          // W12: 512 rows x 128 chunks
            const int r = idx >> 7, k8 = (idx & 127) * 8;
            const float* src = (k8 < 512) ? (W1 + r*512 + k8) : (W2 + r*512 + (k8 - 512));
            float4 a = *(const float4*)src;
            float4 b = *((const float4*)src + 1);
            *(short8*)&W12[r*1024 + k8] = cvt8(a, b);
        } else {                    // W3: 512 rows x 64 chunks
            const int i2 = idx - 65536;
            const int r = i2 >> 6, k8 = (i2 & 63) * 8;
            const float* src = W3 + r*512 + k8;
            float4 a = *(const float4*)src;
            float4 b = *((const float4*)src + 1);
            *(short8*)&W3b[r*512 + k8] = cvt8(a, b);
        }
        return;
    }
    __shared__ double es_l[512];
    __shared__ double red[256];
    int b;
    if (blk < 448) b = ((blk - 384) & 31) >> 1;
    else           b = blk - 448;
    for (int e = tid; e < 512; e += 256) {
        double s = 0.0;
        #pragma unroll
        for (int c = 0; c < 16; ++c) s += part[c*8192 + b*512 + e];
        es_l[e] = s;
    }
    __syncthreads();
    if (blk < 448) {
        const int blk2 = blk - 384;
        const int which = blk2 >> 5;
        const int t = (blk2 & 31)*256 + tid;   // b*512 + i
        const int i = t & 511;
        const float* W = which ? W2 : W1;
        double a = 0.0;
        for (int e = 0; e < 512; ++e) a += (double)W[e*512 + i] * es_l[e];
        u[which*8192 + t] = a;
    } else {
        double a = 0.0;
        for (int e = tid; e < 512; e += 256) a += (double)(b1[e] + b2[e]) * es_l[e];
        red[tid] = a; __syncthreads();
        for (int s = 128; s > 0; s >>= 1) { if (tid < s) red[tid] += red[tid+s]; __syncthreads(); }
        if (tid == 0) cd[b] = red[0];
    }
}

// Fused: Sinv[r] = 1/(X[r,:]·u1[b] + T[r,:]·u2[b] + c[b]) AND XT_bf[r] emission.
// One block per (b, row-group): u1/u2 held in REGISTERS (lane k owns exactly
// the 8 u-elements its X/T chunk needs), amortized over 32 rows.
__global__ __launch_bounds__(256) void s_xt_kernel(
    const float* __restrict__ X, const float* __restrict__ T,
    const double* __restrict__ u, const double* __restrict__ cd,
    float* __restrict__ Sinv, u16* __restrict__ XT)
{
    const int wave = threadIdx.x >> 6, lane = threadIdx.x & 63;
    const int b = blockIdx.x & 15, g = blockIdx.x >> 4;   // g in 0..31
    const int e = lane * 8;
    double u1r[8], u2r[8];
    #pragma unroll
    for (int k = 0; k < 8; ++k) {
        u1r[k] = u[b*512 + e + k];
        u2r[k] = u[8192 + b*512 + e + k];
    }
    const double cb = cd[b];
    #pragma unroll 2
    for (int i = 0; i < 8; ++i) {
        const int j = g*32 + wave*8 + i;     // row-within-b, 0..1023
        const int r = j*16 + b;
        float4 x0 = *(const float4*)&X[r*512 + e];
        float4 x1 = *(const float4*)&X[r*512 + e + 4];
        float4 t0 = *(const float4*)&T[r*512 + e];
        float4 t1 = *(const float4*)&T[r*512 + e + 4];
        double a = 0.0;
        a += (double)x0.x*u1r[0] + (double)x0.y*u1r[1] + (double)x0.z*u1r[2] + (double)x0.w*u1r[3];
        a += (double)x1.x*u1r[4] + (double)x1.y*u1r[5] + (double)x1.z*u1r[6] + (double)x1.w*u1r[7];
        a += (double)t0.x*u2r[0] + (double)t0.y*u2r[1] + (double)t0.z*u2r[2] + (double)t0.w*u2r[3];
        a += (double)t1.x*u2r[4] + (double)t1.y*u2r[5] + (double)t1.z*u2r[6] + (double)t1.w*u2r[7];
        *(short8*)&XT[r*1024 + e]       = cvt8(x0, x1);
        *(short8*)&XT[r*1024 + 512 + e] = cvt8(t0, t1);
        #pragma unroll
        for (int off = 32; off > 0; off >>= 1) a += __shfl_down(a, off, 64);
        if (lane == 0) Sinv[r] = (float)(1.0 / (a + cb));
    }
}

extern "C" void kernel_launch(void* const* d_in, const int* in_sizes, int n_in,
                              void* d_out, int out_size, void* d_ws, size_t ws_size,
                              hipStream_t stream)
{
    const float* X   = (const float*)d_in[0];
    const float* Enc = (const float*)d_in[1];
    const float* T   = (const float*)d_in[2];
    const float* W1  = (const float*)d_in[3];
    const float* b1  = (const float*)d_in[4];
    const float* W2  = (const float*)d_in[5];
    const float* b2  = (const float*)d_in[6];
    const float* W3  = (const float*)d_in[7];
    const float* b3  = (const float*)d_in[8];
    float* out = (float*)d_out;

    char* w = (char*)d_ws;
    u16*    dvals_bf = (u16*)(w);                 // 16,777,216 B
    u16*    EncT_bf  = (u16*)(w + 16777216);      // 16,777,216 B
    u16*    Gram_bf  = (u16*)(w + 33554432);      //  8,388,608 B
    u16*    HT_bf    = (u16*)(w + 41943040);      //  8,388,608 B
    u16*    W12      = (u16*)(w + 50331648);      //  1,048,576 B
    u16*    W3b      = (u16*)(w + 51380224);      //    524,288 B
    double* part     = (double*)(w + 51904512);   //  1,048,576 B (16 x 8192 f64)
    double* u        = (double*)(w + 52953088);   //    131,072 B
    double* cd       = (double*)(w + 53084160);   //        128 B
    float*  Sinv     = (float*)(w + 53084288);    //     65,536 B  (end 53,149,824)
    // XT_bf lives in d_out (exactly 32 MiB); consumed by gemm<1>, then gemm<4>
    // overwrites d_out with the real output.
    u16*    XTb      = (u16*)d_out;

    dim3 blk(256);
    enct_kernel <<<dim3(8, 16, 16), blk, 0, stream>>>(Enc, EncT_bf, part);
    prep_small  <<<dim3(464),       blk, 0, stream>>>(W1, W2, W3, b1, b2, part, W12, W3b, u, cd);
    s_xt_kernel <<<dim3(512),       blk, 0, stream>>>(X, T, u, cd, Sinv, XTb);

    // Gram[b] = Enc_b^T x Enc_b   (both operands = EncT_bf rows)
    gemm_async<5><<<dim3(4, 8, 16),  blk, 0, stream>>>(EncT_bf, EncT_bf, b1, b2, b3, Sinv, Gram_bf, out);
    // HT[b] = W3 x Gram_b  (Gram symmetric)
    gemm_async<6><<<dim3(4, 8, 16),  blk, 0, stream>>>(W3b, Gram_bf, b1, b2, b3, Sinv, HT_bf, out);
    // dvals = XT x W12^T + b1 + b2
    gemm_async<1><<<dim3(4, 128, 1), blk, 0, stream>>>(XTb, W12, b1, b2, b3, Sinv, dvals_bf, out);
    // out[l,b,i] = Sinv * (dvals x HT_b^T) + b3
    gemm_async<4><<<dim3(4, 8, 16),  blk, 0, stream>>>(dvals_bf, HT_bf, b1, b2, b3, Sinv, dvals_bf, out);
}